// Round 1
// 367.381 us; speedup vs baseline: 1.0916x; 1.0916x over previous
//
#include <hip/hip_runtime.h>
#include <hip/hip_bf16.h>
#include <math.h>

// Block_46643344834722: pre-norm attention block, B=512 D=2048 H=16 DH=128.
// R4: BK=64 stages with both-sides XOR swizzle (pre-swizzled global source,
// swizzled ds_read_b128 -> conflict-free), 128x128 tiles w/ 64x64 wave-tiles,
// DEPTH=3 circular pipeline; split-K (+fp32 reduce) for the N=2048 GEMMs;
// 64x64 transpose with 128B bf16x8 writes.

#define DDIM 2048
#define HHEADS 16
#define DHEAD 128
#define BROWS 512
#define LN_EPS 1e-5f

typedef __bf16 bf16x8_t __attribute__((ext_vector_type(8)));
typedef float f32x4_t __attribute__((ext_vector_type(4)));

#define GLD16(gptr, lptr)                                                     \
    __builtin_amdgcn_global_load_lds(                                         \
        (const __attribute__((address_space(1))) void*)(gptr),                \
        (__attribute__((address_space(3))) void*)(lptr), 16, 0, 0)

// ---------------------------------------------------------------- LayerNorm
__global__ __launch_bounds__(256) void ln_kernel(const float* __restrict__ x,
                                                 const float* __restrict__ g,
                                                 const float* __restrict__ b,
                                                 __bf16* __restrict__ out) {
    const int row = blockIdx.x;
    const int tid = threadIdx.x;
    const float4* x4 = (const float4*)(x + (size_t)row * DDIM);
    float4 a = x4[2 * tid];
    float4 c = x4[2 * tid + 1];
    float s  = a.x + a.y + a.z + a.w + c.x + c.y + c.z + c.w;
    float s2 = a.x*a.x + a.y*a.y + a.z*a.z + a.w*a.w
             + c.x*c.x + c.y*c.y + c.z*c.z + c.w*c.w;
    #pragma unroll
    for (int off = 32; off > 0; off >>= 1) {
        s  += __shfl_down(s, off);
        s2 += __shfl_down(s2, off);
    }
    __shared__ float ps[4], ps2[4];
    __shared__ float mean_s, rstd_s;
    const int lane = tid & 63, w = tid >> 6;
    if (lane == 0) { ps[w] = s; ps2[w] = s2; }
    __syncthreads();
    if (tid == 0) {
        float S  = ps[0] + ps[1] + ps[2] + ps[3];
        float S2 = ps2[0] + ps2[1] + ps2[2] + ps2[3];
        float m  = S * (1.0f / DDIM);
        float var = S2 * (1.0f / DDIM) - m * m;
        mean_s = m;
        rstd_s = rsqrtf(var + LN_EPS);
    }
    __syncthreads();
    const float m = mean_s, r = rstd_s;
    const float4* g4 = (const float4*)g;
    const float4* b4 = (const float4*)b;
    float4 ga = g4[2 * tid], gb = g4[2 * tid + 1];
    float4 ba = b4[2 * tid], bb = b4[2 * tid + 1];
    bf16x8_t o;
    o[0] = (__bf16)((a.x - m) * r * ga.x + ba.x);
    o[1] = (__bf16)((a.y - m) * r * ga.y + ba.y);
    o[2] = (__bf16)((a.z - m) * r * ga.z + ba.z);
    o[3] = (__bf16)((a.w - m) * r * ga.w + ba.w);
    o[4] = (__bf16)((c.x - m) * r * gb.x + bb.x);
    o[5] = (__bf16)((c.y - m) * r * gb.y + bb.y);
    o[6] = (__bf16)((c.z - m) * r * gb.z + bb.z);
    o[7] = (__bf16)((c.w - m) * r * gb.w + bb.w);
    *(bf16x8_t*)(out + (size_t)row * DDIM + tid * 8) = o;
}

// ---------------------------------------------------------------- Transpose
// src fp32 [R,C] (batched) -> dst bf16 [C,R] (batched, stride R*C).
// 64x64 tile; writes are 128B bf16x8 rows (coalesced).
__global__ __launch_bounds__(256) void transpose_kernel(
    const float* __restrict__ src, __bf16* __restrict__ dst, int R, int C) {
    __shared__ float tile[64][65];
    const size_t bofs = (size_t)blockIdx.z * R * C;
    src += bofs;
    dst += bofs;
    const int c0 = blockIdx.x * 64, r0 = blockIdx.y * 64;
    const int t = threadIdx.x;
    const int rr = t >> 4, cc = (t & 15) * 4;
    #pragma unroll
    for (int p = 0; p < 4; p++) {
        const float4 v =
            *(const float4*)(src + (size_t)(r0 + rr + 16 * p) * C + c0 + cc);
        tile[rr + 16 * p][cc]     = v.x;
        tile[rr + 16 * p][cc + 1] = v.y;
        tile[rr + 16 * p][cc + 2] = v.z;
        tile[rr + 16 * p][cc + 3] = v.w;
    }
    __syncthreads();
    const int slot = t & 7;
    #pragma unroll
    for (int p = 0; p < 2; p++) {
        const int c = (t >> 3) + 32 * p;
        bf16x8_t o;
        #pragma unroll
        for (int j = 0; j < 8; j++)
            o[j] = (__bf16)tile[slot * 8 + j][c];
        *(bf16x8_t*)(dst + (size_t)(c0 + c) * R + r0 + slot * 8) = o;
    }
}

// ---------------------------------------------------------------- fused bias
__global__ __launch_bounds__(256) void fuse_bias_kernel(
    const float* __restrict__ bq, const float* __restrict__ bk,
    const float* __restrict__ bv, float* __restrict__ fb) {
    const int i = blockIdx.x * 256 + threadIdx.x;  // 0..6143
    float v;
    if (i < 2048) v = bq[i];
    else if (i < 4096) v = bk[i - 2048];
    else v = bv[i - 4096];
    fb[i] = v;
}

// ---------------------------------------------------------------- GEMM (B^T)
// C[M,N] = A[M,K] @ Bt[N,K]^T (+bias +Res, relu?).  bf16 in, fp32 acc.
// BK=64 stages (128B rows). LDS is linear (global_load_lds), but the global
// SOURCE k-slot is pre-permuted s=(l&7)^(l>>3) so the fragment read
// j = (h*4+quad) ^ (row&7) is the matching involution -> 2-way (free) banks.
// SPLITZ>1: blockIdx.z takes K/SPLITZ slice, writes raw fp32 partials.
template <int TM, int TN, int DEPTH, int SPLITZ, int OUT_BF16, int RELU, int RES>
__global__ __launch_bounds__(256) void gemm_bt(
    const __bf16* __restrict__ A, int K,
    const __bf16* __restrict__ Bt,
    const float* __restrict__ bias,
    const float* __restrict__ Res,
    void* __restrict__ Cout, int N) {
    constexpr int STG = (TM + TN) * 64;  // bf16 elems per stage (BK=64)
    __shared__ __align__(16) __bf16 smem[DEPTH * STG];

    const int tid = threadIdx.x;
    const int w = tid >> 6, lane = tid & 63;
    const int m0 = blockIdx.y * TM, n0 = blockIdx.x * TN;

    const int Kloc = K / SPLITZ;
    const int kb = blockIdx.z * Kloc;
    const int NK = Kloc / 64;

    constexpr int NT = (TM + TN) / 8;  // 8-row (1KB) chunks per stage
    constexpr int NI = NT / 4;         // chunks per wave

    // staging: chunk t covers rows 8t..8t+7 (A rows then B rows).
    // lane l -> row 8t+(l>>3); source k-slot pre-swizzled (l&7)^(l>>3).
    const int srow = lane >> 3;
    const int sslot = (lane & 7) ^ srow;

    const __bf16* srcs[NI];
    int toff[NI];
    #pragma unroll
    for (int i = 0; i < NI; i++) {
        const int t = w + 4 * i;
        toff[i] = t * 512;  // 8 rows * 64 elems
        const int r = t * 8 + srow;
        srcs[i] = (r < TM)
                      ? A + (size_t)(m0 + r) * K + kb + sslot * 8
                      : Bt + (size_t)(n0 + r - TM) * K + kb + sslot * 8;
    }

    constexpr int MI = TM / 32;  // wave-tile = (TM/2) x (TN/2)
    constexpr int NJ = TN / 32;
    const int wm = (w >> 1) * (TM / 2), wn = (w & 1) * (TN / 2);
    const int fm = lane & 15, quad = lane >> 4;
    const int f7 = fm & 7;

    // fragment LDS byte offsets within a stage, per k-half h:
    // byte = row*128 + ((h*4+quad) ^ (row&7))*16   (row&7 == fm&7 here)
    int aoff[2][MI], boff[2][NJ];
    #pragma unroll
    for (int h = 0; h < 2; h++) {
        const int sl = ((h * 4 + quad) ^ f7) * 16;
        #pragma unroll
        for (int i = 0; i < MI; i++)
            aoff[h][i] = (wm + 16 * i + fm) * 128 + sl;
        #pragma unroll
        for (int j = 0; j < NJ; j++)
            boff[h][j] = (TM + wn + 16 * j + fm) * 128 + sl;
    }

    f32x4_t acc[MI][NJ] = {};

    // prologue: fill all DEPTH stages
    #pragma unroll
    for (int d = 0; d < DEPTH; d++)
        #pragma unroll
        for (int i = 0; i < NI; i++)
            GLD16(srcs[i] + d * 64, smem + d * STG + toff[i]);

    for (int ks = 0; ks < NK; ks++) {
        const char* st = (const char*)smem + (ks % DEPTH) * (STG * 2);
        // oldest stage complete: <= (DEPTH-1)*NI of this wave's loads pending
        asm volatile("s_waitcnt vmcnt(%0)\n\ts_barrier"
                     :: "i"((DEPTH - 1) * NI) : "memory");

        bf16x8_t a[2][MI], b[2][NJ];
        #pragma unroll
        for (int h = 0; h < 2; h++) {
            #pragma unroll
            for (int i = 0; i < MI; i++)
                a[h][i] = *(const bf16x8_t*)(st + aoff[h][i]);
            #pragma unroll
            for (int j = 0; j < NJ; j++)
                b[h][j] = *(const bf16x8_t*)(st + boff[h][j]);
        }
        #pragma unroll
        for (int i = 0; i < MI; i++)
            #pragma unroll
            for (int j = 0; j < NJ; j++) {
                acc[i][j] = __builtin_amdgcn_mfma_f32_16x16x32_bf16(
                    a[0][i], b[0][j], acc[i][j], 0, 0, 0);
                acc[i][j] = __builtin_amdgcn_mfma_f32_16x16x32_bf16(
                    a[1][i], b[1][j], acc[i][j], 0, 0, 0);
            }

        // all waves done reading this slot before refilling it
        asm volatile("s_waitcnt lgkmcnt(0)\n\ts_barrier" ::: "memory");
        if (ks + DEPTH < NK) {
            __bf16* dst = smem + (ks % DEPTH) * STG;
            #pragma unroll
            for (int i = 0; i < NI; i++)
                GLD16(srcs[i] + (size_t)(ks + DEPTH) * 64, dst + toff[i]);
        }
    }

    // epilogue: C/D layout col=fm, row=quad*4+r
    if (SPLITZ > 1) {
        float* P = (float*)Cout + (size_t)blockIdx.z * (gridDim.y * TM) * N;
        #pragma unroll
        for (int i = 0; i < MI; i++)
            #pragma unroll
            for (int j = 0; j < NJ; j++) {
                const int col = n0 + wn + 16 * j + fm;
                #pragma unroll
                for (int r = 0; r < 4; r++) {
                    const int row = m0 + wm + 16 * i + quad * 4 + r;
                    P[(size_t)row * N + col] = acc[i][j][r];
                }
            }
    } else {
        #pragma unroll
        for (int i = 0; i < MI; i++)
            #pragma unroll
            for (int j = 0; j < NJ; j++) {
                const int col = n0 + wn + 16 * j + fm;
                const float bcol = bias[col];
                #pragma unroll
                for (int r = 0; r < 4; r++) {
                    const int row = m0 + wm + 16 * i + quad * 4 + r;
                    float val = acc[i][j][r] + bcol;
                    if (RES) val += Res[(size_t)row * N + col];
                    if (RELU) val = fmaxf(val, 0.0f);
                    if (OUT_BF16)
                        ((__bf16*)Cout)[(size_t)row * N + col] = (__bf16)val;
                    else
                        ((float*)Cout)[(size_t)row * N + col] = val;
                }
            }
    }
}

// ---------------------------------------------------------------- split-K sum
// out[512,2048] = Res + bias(per-col) + sum_s part[s]   (float4 per thread)
template <int NS>
__global__ __launch_bounds__(256) void reduce_splitk(
    const float* __restrict__ part, const float* __restrict__ Res,
    const float* __restrict__ bias, float* __restrict__ out) {
    const int idx = blockIdx.x * 256 + threadIdx.x;  // 0..262143 float4s
    const float4 b4 = ((const float4*)bias)[idx & 511];
    float4 r = ((const float4*)Res)[idx];
    #pragma unroll
    for (int s = 0; s < NS; s++) {
        const float4 p = ((const float4*)part)[(size_t)s * 262144 + idx];
        r.x += p.x; r.y += p.y; r.z += p.z; r.w += p.w;
    }
    r.x += b4.x; r.y += b4.y; r.z += b4.z; r.w += b4.w;
    ((float4*)out)[idx] = r;
}

// ---------------------------------------------------------------- Attention
// qkv bf16 [512, 6144] (q|k|v per row, each [H,DH]); o bf16 [512, 2048].
__global__ __launch_bounds__(128) void attn_kernel(
    const __bf16* __restrict__ qkv, __bf16* __restrict__ o) {
    const int bh = blockIdx.x;  // b*H + h
    const int b = bh >> 4, h = bh & 15;
    const size_t base = (size_t)b * (3 * DDIM) + h * DHEAD;
    const int tid = threadIdx.x;
    __shared__ float ks[DHEAD], vs[DHEAD];
    ks[tid] = (float)qkv[base + DDIM + tid];
    vs[tid] = (float)qkv[base + 2 * DDIM + tid];
    __syncthreads();
    const float a = (float)qkv[base + tid] * 0.08838834764831845f;  // /sqrt(128)
    float den = 0.0f, num = 0.0f;
    #pragma unroll 8
    for (int j = 0; j < DHEAD; j++) {
        float e = __expf(a * ks[j]);
        den += e;
        num += e * vs[j];
    }
    o[(size_t)b * DDIM + h * DHEAD + tid] = (__bf16)(num / den);
}

// ---------------------------------------------------------------- launch
extern "C" void kernel_launch(void* const* d_in, const int* in_sizes, int n_in,
                              void* d_out, int out_size, void* d_ws, size_t ws_size,
                              hipStream_t stream) {
    const float* x   = (const float*)d_in[0];
    const float* Wq  = (const float*)d_in[1];
    const float* bq  = (const float*)d_in[2];
    const float* Wk  = (const float*)d_in[3];
    const float* bk  = (const float*)d_in[4];
    const float* Wv  = (const float*)d_in[5];
    const float* bv  = (const float*)d_in[6];
    const float* Wo  = (const float*)d_in[7];
    const float* bo  = (const float*)d_in[8];
    const float* W1  = (const float*)d_in[9];
    const float* b1  = (const float*)d_in[10];
    const float* W2  = (const float*)d_in[11];
    const float* b2  = (const float*)d_in[12];
    const float* g1  = (const float*)d_in[13];
    const float* be1 = (const float*)d_in[14];
    const float* g2  = (const float*)d_in[15];
    const float* be2 = (const float*)d_in[16];
    float* out = (float*)d_out;

    // ---- workspace layout (bytes), lifetime-overlapped ----
    char* base = (char*)d_ws;
    float*  fb     = (float*)(base + 0);              //   24,576 B
    __bf16* bt_qkv = (__bf16*)(base + 32768);         // 25,165,824 B  [6144,2048]
    char*   slotA  = base + 32768 + 25165824;         // 33,554,432 B
    char*   slotB  = slotA + 33554432;                // 33,554,432 B
    // activations in dead regions:
    __bf16* h   = (__bf16*)(slotB + 0);               // bf16 [512,2048]
    __bf16* qkv = (__bf16*)(slotB + 2097152);         // bf16 [512,6144]
    __bf16* ob  = (__bf16*)(slotB + 8388608);         // bf16 [512,2048]
    float*  woP = (float*)(slotB + 10485760);         // fp32 [2][512,2048]
    float*  w2P = (float*)(slotB + 0);                // fp32 [4][512,2048] (W1t dead)
    float*  x1  = (float*)((char*)bt_qkv + 0);        // fp32 [512,2048]
    __bf16* h2  = (__bf16*)((char*)bt_qkv + 4194304); // bf16 [512,2048]
    __bf16* t   = (__bf16*)((char*)bt_qkv + 6291456); // bf16 [512,8192]
    __bf16* Wot = (__bf16*)slotA;                     // [2048,2048]
    __bf16* W1t = (__bf16*)slotB;                     // [8192,2048]
    __bf16* W2t = (__bf16*)slotA;                     // [2048,8192]

    fuse_bias_kernel<<<24, 256, 0, stream>>>(bq, bk, bv, fb);

    // transposed bf16 weights: B^T[N,K]
    transpose_kernel<<<dim3(2, 32, 16), 256, 0, stream>>>(Wq, bt_qkv, DDIM, DHEAD);
    transpose_kernel<<<dim3(2, 32, 16), 256, 0, stream>>>(Wk, bt_qkv + 2048 * 2048, DDIM, DHEAD);
    transpose_kernel<<<dim3(2, 32, 16), 256, 0, stream>>>(Wv, bt_qkv + 2 * 2048 * 2048, DDIM, DHEAD);
    transpose_kernel<<<dim3(32, 32, 1), 256, 0, stream>>>(Wo, Wot, DDIM, DDIM);

    // h = LN(x)
    ln_kernel<<<BROWS, 256, 0, stream>>>(x, g1, be1, h);

    // qkv = h @ [Wq|Wk|Wv] + [bq|bk|bv]   -> bf16 [512,6144]
    gemm_bt<128, 128, 3, 1, 1, 0, 0><<<dim3(48, 4), 256, 0, stream>>>(
        h, DDIM, bt_qkv, fb, nullptr, qkv, 3 * DDIM);

    attn_kernel<<<BROWS * HHEADS, 128, 0, stream>>>(qkv, ob);

    // x1 = x + ob @ Wo + bo   (split-K=2 partials + fused reduce)
    gemm_bt<64, 128, 4, 2, 0, 0, 0><<<dim3(16, 8, 2), 256, 0, stream>>>(
        ob, DDIM, Wot, nullptr, nullptr, woP, DDIM);
    reduce_splitk<2><<<1024, 256, 0, stream>>>(woP, x, bo, x1);

    // late transposes into now-dead regions
    transpose_kernel<<<dim3(128, 32, 1), 256, 0, stream>>>(W1, W1t, DDIM, 4 * DDIM);
    transpose_kernel<<<dim3(32, 128, 1), 256, 0, stream>>>(W2, W2t, 4 * DDIM, DDIM);

    // h2 = LN(x1)
    ln_kernel<<<BROWS, 256, 0, stream>>>(x1, g2, be2, h2);

    // t = relu(h2 @ W1 + b1)  -> bf16 [512,8192]
    gemm_bt<128, 128, 3, 1, 1, 1, 0><<<dim3(64, 4), 256, 0, stream>>>(
        h2, DDIM, W1t, b1, nullptr, t, 4 * DDIM);

    // out = x1 + t @ W2 + b2   (split-K=4 partials + fused reduce)
    gemm_bt<128, 128, 3, 4, 0, 0, 0><<<dim3(16, 4, 4), 256, 0, stream>>>(
        t, 4 * DDIM, W2t, nullptr, nullptr, w2P, DDIM);
    reduce_splitk<4><<<1024, 256, 0, stream>>>(w2P, x1, b2, out);
}

// Round 2
// 351.779 us; speedup vs baseline: 1.1400x; 1.0444x over previous
//
#include <hip/hip_runtime.h>
#include <hip/hip_bf16.h>
#include <math.h>

// Block_46643344834722: pre-norm attention block, B=512 D=2048 H=16 DH=128.
// R5: gemm goes 512-thread / 8-wave with k-half-split waves (same LDS traffic,
// 2 waves/SIMD for latency hiding) + LDS acc-merge epilogue; split-K=4 for
// Wo and W2 (full-chip grids); qkv bias folded into epilogue; 3 qkv
// transposes merged into one dispatch; Wo-reduce fused with LN2.

#define DDIM 2048
#define HHEADS 16
#define DHEAD 128
#define BROWS 512
#define LN_EPS 1e-5f

typedef __bf16 bf16x8_t __attribute__((ext_vector_type(8)));
typedef float f32x4_t __attribute__((ext_vector_type(4)));

#define GLD16(gptr, lptr)                                                     \
    __builtin_amdgcn_global_load_lds(                                         \
        (const __attribute__((address_space(1))) void*)(gptr),                \
        (__attribute__((address_space(3))) void*)(lptr), 16, 0, 0)

// ---------------------------------------------------------------- LayerNorm
__global__ __launch_bounds__(256) void ln_kernel(const float* __restrict__ x,
                                                 const float* __restrict__ g,
                                                 const float* __restrict__ b,
                                                 __bf16* __restrict__ out) {
    const int row = blockIdx.x;
    const int tid = threadIdx.x;
    const float4* x4 = (const float4*)(x + (size_t)row * DDIM);
    float4 a = x4[2 * tid];
    float4 c = x4[2 * tid + 1];
    float s  = a.x + a.y + a.z + a.w + c.x + c.y + c.z + c.w;
    float s2 = a.x*a.x + a.y*a.y + a.z*a.z + a.w*a.w
             + c.x*c.x + c.y*c.y + c.z*c.z + c.w*c.w;
    #pragma unroll
    for (int off = 32; off > 0; off >>= 1) {
        s  += __shfl_down(s, off);
        s2 += __shfl_down(s2, off);
    }
    __shared__ float ps[4], ps2[4];
    __shared__ float mean_s, rstd_s;
    const int lane = tid & 63, w = tid >> 6;
    if (lane == 0) { ps[w] = s; ps2[w] = s2; }
    __syncthreads();
    if (tid == 0) {
        float S  = ps[0] + ps[1] + ps[2] + ps[3];
        float S2 = ps2[0] + ps2[1] + ps2[2] + ps2[3];
        float m  = S * (1.0f / DDIM);
        float var = S2 * (1.0f / DDIM) - m * m;
        mean_s = m;
        rstd_s = rsqrtf(var + LN_EPS);
    }
    __syncthreads();
    const float m = mean_s, r = rstd_s;
    const float4* g4 = (const float4*)g;
    const float4* b4 = (const float4*)b;
    float4 ga = g4[2 * tid], gb = g4[2 * tid + 1];
    float4 ba = b4[2 * tid], bb = b4[2 * tid + 1];
    bf16x8_t o;
    o[0] = (__bf16)((a.x - m) * r * ga.x + ba.x);
    o[1] = (__bf16)((a.y - m) * r * ga.y + ba.y);
    o[2] = (__bf16)((a.z - m) * r * ga.z + ba.z);
    o[3] = (__bf16)((a.w - m) * r * ga.w + ba.w);
    o[4] = (__bf16)((c.x - m) * r * gb.x + bb.x);
    o[5] = (__bf16)((c.y - m) * r * gb.y + bb.y);
    o[6] = (__bf16)((c.z - m) * r * gb.z + bb.z);
    o[7] = (__bf16)((c.w - m) * r * gb.w + bb.w);
    *(bf16x8_t*)(out + (size_t)row * DDIM + tid * 8) = o;
}

// ---------------------------------------------------------------- Transpose
// src fp32 [R,C] (batched) -> dst bf16 [C,R] (batched, stride R*C).
__global__ __launch_bounds__(256) void transpose_kernel(
    const float* __restrict__ src, __bf16* __restrict__ dst, int R, int C) {
    __shared__ float tile[64][65];
    const size_t bofs = (size_t)blockIdx.z * R * C;
    src += bofs;
    dst += bofs;
    const int c0 = blockIdx.x * 64, r0 = blockIdx.y * 64;
    const int t = threadIdx.x;
    const int rr = t >> 4, cc = (t & 15) * 4;
    #pragma unroll
    for (int p = 0; p < 4; p++) {
        const float4 v =
            *(const float4*)(src + (size_t)(r0 + rr + 16 * p) * C + c0 + cc);
        tile[rr + 16 * p][cc]     = v.x;
        tile[rr + 16 * p][cc + 1] = v.y;
        tile[rr + 16 * p][cc + 2] = v.z;
        tile[rr + 16 * p][cc + 3] = v.w;
    }
    __syncthreads();
    const int slot = t & 7;
    #pragma unroll
    for (int p = 0; p < 2; p++) {
        const int c = (t >> 3) + 32 * p;
        bf16x8_t o;
        #pragma unroll
        for (int j = 0; j < 8; j++)
            o[j] = (__bf16)tile[slot * 8 + j][c];
        *(bf16x8_t*)(dst + (size_t)(c0 + c) * R + r0 + slot * 8) = o;
    }
}

// Merged q/k/v weight transpose: z = which*16 + head; [2048,128] -> [128*?]^T
__global__ __launch_bounds__(256) void transpose_qkv_kernel(
    const float* __restrict__ Wq, const float* __restrict__ Wk,
    const float* __restrict__ Wv, __bf16* __restrict__ dstall) {
    __shared__ float tile[64][65];
    const int z = blockIdx.z, which = z >> 4, hd = z & 15;
    const float* src = (which == 0) ? Wq : (which == 1) ? Wk : Wv;
    src += (size_t)hd * DDIM * DHEAD;
    __bf16* dst = dstall + (size_t)which * DDIM * DDIM + (size_t)hd * DDIM * DHEAD;
    const int R = DDIM, C = DHEAD;
    const int c0 = blockIdx.x * 64, r0 = blockIdx.y * 64;
    const int t = threadIdx.x;
    const int rr = t >> 4, cc = (t & 15) * 4;
    #pragma unroll
    for (int p = 0; p < 4; p++) {
        const float4 v =
            *(const float4*)(src + (size_t)(r0 + rr + 16 * p) * C + c0 + cc);
        tile[rr + 16 * p][cc]     = v.x;
        tile[rr + 16 * p][cc + 1] = v.y;
        tile[rr + 16 * p][cc + 2] = v.z;
        tile[rr + 16 * p][cc + 3] = v.w;
    }
    __syncthreads();
    const int slot = t & 7;
    #pragma unroll
    for (int p = 0; p < 2; p++) {
        const int c = (t >> 3) + 32 * p;
        bf16x8_t o;
        #pragma unroll
        for (int j = 0; j < 8; j++)
            o[j] = (__bf16)tile[slot * 8 + j][c];
        *(bf16x8_t*)(dst + (size_t)(c0 + c) * R + r0 + slot * 8) = o;
    }
}

// ---------------------------------------------------------------- GEMM (B^T)
// C[M,N] = A[M,K] @ Bt[N,K]^T (+bias +Res, relu?).  bf16 in, fp32 acc.
// 128x128 tile, 512 threads. BK=64 stages, both-sides XOR swizzle
// (pre-swizzled global source, swizzled ds_read_b128 -> 2-way banks = free).
// 8 waves: wg=w&3 picks a 64x64 wave-tile, kh=w>>2 picks the k-half of each
// stage.  Same per-CU LDS traffic as the 4-wave variant, but 2 waves/SIMD.
// Epilogue merges the two k-half accumulators through LDS.
// SPLITZ>1: blockIdx.z takes K/SPLITZ slice, writes raw fp32 partials.
template <int DEPTH, int SPLITZ, int OUT_BF16, int RELU, int RES, int BIAS3>
__global__ __launch_bounds__(512) void gemm_bt(
    const __bf16* __restrict__ A, int K,
    const __bf16* __restrict__ Bt,
    const float* __restrict__ bias, const float* __restrict__ biasB,
    const float* __restrict__ biasC,
    const float* __restrict__ Res,
    void* __restrict__ Cout, int N) {
    constexpr int TM = 128, TN = 128;
    constexpr int STG = (TM + TN) * 64;  // bf16 elems per stage (BK=64)
    __shared__ __align__(16) __bf16 smem[DEPTH * STG];

    const int tid = threadIdx.x;
    const int w = tid >> 6, lane = tid & 63;
    const int m0 = blockIdx.y * TM, n0 = blockIdx.x * TN;

    const int Kloc = K / SPLITZ;
    const int kb = blockIdx.z * Kloc;
    const int NK = Kloc / 64;

    constexpr int NT = (TM + TN) / 8;  // 8-row (1KB) chunks per stage
    constexpr int NI = NT / 8;         // chunks per wave (4)

    // staging: chunk t covers rows 8t..8t+7 (A rows then B rows).
    // lane l -> row 8t+(l>>3); source k-slot pre-swizzled (l&7)^(l>>3).
    const int srow = lane >> 3;
    const int sslot = (lane & 7) ^ srow;

    const __bf16* srcs[NI];
    int toff[NI];
    #pragma unroll
    for (int i = 0; i < NI; i++) {
        const int t = w + 8 * i;
        toff[i] = t * 512;  // 8 rows * 64 elems
        const int r = t * 8 + srow;
        srcs[i] = (r < TM)
                      ? A + (size_t)(m0 + r) * K + kb + sslot * 8
                      : Bt + (size_t)(n0 + r - TM) * K + kb + sslot * 8;
    }

    constexpr int MI = 4, NJ = 4;        // 64x64 wave-tile in 16-units
    const int wg = w & 3, kh = w >> 2;   // wave-tile id, k-half id
    const int wm = (wg >> 1) * 64, wn = (wg & 1) * 64;
    const int fm = lane & 15, quad = lane >> 4;
    const int f7 = fm & 7;

    // fragment LDS byte offsets within a stage (own k-half only):
    // byte = row*128 + ((kh*4+quad) ^ (row&7))*16
    const int sl = ((kh * 4 + quad) ^ f7) * 16;
    int aoff[MI], boff[NJ];
    #pragma unroll
    for (int i = 0; i < MI; i++)
        aoff[i] = (wm + 16 * i + fm) * 128 + sl;
    #pragma unroll
    for (int j = 0; j < NJ; j++)
        boff[j] = (TM + wn + 16 * j + fm) * 128 + sl;

    f32x4_t acc[MI][NJ] = {};

    // prologue: fill all DEPTH stages
    #pragma unroll
    for (int d = 0; d < DEPTH; d++)
        #pragma unroll
        for (int i = 0; i < NI; i++)
            GLD16(srcs[i] + d * 64, smem + d * STG + toff[i]);

    for (int ks = 0; ks < NK; ks++) {
        const char* st = (const char*)smem + (ks % DEPTH) * (STG * 2);
        // oldest stage complete: <= (DEPTH-1)*NI of this wave's loads pending
        asm volatile("s_waitcnt vmcnt(%0)\n\ts_barrier"
                     :: "i"((DEPTH - 1) * NI) : "memory");

        bf16x8_t a[MI], b[NJ];
        #pragma unroll
        for (int i = 0; i < MI; i++)
            a[i] = *(const bf16x8_t*)(st + aoff[i]);
        #pragma unroll
        for (int j = 0; j < NJ; j++)
            b[j] = *(const bf16x8_t*)(st + boff[j]);
        #pragma unroll
        for (int i = 0; i < MI; i++)
            #pragma unroll
            for (int j = 0; j < NJ; j++)
                acc[i][j] = __builtin_amdgcn_mfma_f32_16x16x32_bf16(
                    a[i], b[j], acc[i][j], 0, 0, 0);

        // all waves done reading this slot before refilling it
        asm volatile("s_waitcnt lgkmcnt(0)\n\ts_barrier" ::: "memory");
        if (ks + DEPTH < NK) {
            __bf16* dst = smem + (ks % DEPTH) * STG;
            #pragma unroll
            for (int i = 0; i < NI; i++)
                GLD16(srcs[i] + (size_t)(ks + DEPTH) * 64, dst + toff[i]);
        }
    }

    // ---- merge the two k-half accumulators through LDS (reuses stages) ----
    char* mrg = (char*)smem + wg * 16384;
    if (kh == 1) {
        #pragma unroll
        for (int i = 0; i < MI; i++)
            #pragma unroll
            for (int j = 0; j < NJ; j++)
                *(f32x4_t*)(mrg + (((i * NJ + j) * 64) + lane) * 16) = acc[i][j];
    }
    __syncthreads();
    if (kh == 1) return;
    #pragma unroll
    for (int i = 0; i < MI; i++)
        #pragma unroll
        for (int j = 0; j < NJ; j++) {
            const f32x4_t p = *(const f32x4_t*)(mrg + (((i * NJ + j) * 64) + lane) * 16);
            acc[i][j][0] += p[0]; acc[i][j][1] += p[1];
            acc[i][j][2] += p[2]; acc[i][j][3] += p[3];
        }

    // epilogue: C/D layout col=fm, row=quad*4+r  (waves 0..3 only)
    if (SPLITZ > 1) {
        float* P = (float*)Cout + (size_t)blockIdx.z * (gridDim.y * TM) * N;
        #pragma unroll
        for (int i = 0; i < MI; i++)
            #pragma unroll
            for (int j = 0; j < NJ; j++) {
                const int col = n0 + wn + 16 * j + fm;
                #pragma unroll
                for (int r = 0; r < 4; r++) {
                    const int row = m0 + wm + 16 * i + quad * 4 + r;
                    P[(size_t)row * N + col] = acc[i][j][r];
                }
            }
    } else {
        const float* bp = bias;
        if (BIAS3) {  // q|k|v segment select, uniform per block (n0 mult of 128)
            const int seg = n0 >> 11;
            bp = (seg == 0) ? bias : (seg == 1) ? biasB : biasC;
        }
        #pragma unroll
        for (int i = 0; i < MI; i++)
            #pragma unroll
            for (int j = 0; j < NJ; j++) {
                const int col = n0 + wn + 16 * j + fm;
                const float bcol = BIAS3 ? bp[col & 2047] : bp[col];
                #pragma unroll
                for (int r = 0; r < 4; r++) {
                    const int row = m0 + wm + 16 * i + quad * 4 + r;
                    float val = acc[i][j][r] + bcol;
                    if (RES) val += Res[(size_t)row * N + col];
                    if (RELU) val = fmaxf(val, 0.0f);
                    if (OUT_BF16)
                        ((__bf16*)Cout)[(size_t)row * N + col] = (__bf16)val;
                    else
                        ((float*)Cout)[(size_t)row * N + col] = val;
                }
            }
    }
}

// ---------------------------------------------------------------- split-K sum
// out[512,2048] = Res + bias(per-col) + sum_s part[s]   (float4 per thread)
template <int NS>
__global__ __launch_bounds__(256) void reduce_splitk(
    const float* __restrict__ part, const float* __restrict__ Res,
    const float* __restrict__ bias, float* __restrict__ out) {
    const int idx = blockIdx.x * 256 + threadIdx.x;  // 0..262143 float4s
    const float4 b4 = ((const float4*)bias)[idx & 511];
    float4 r = ((const float4*)Res)[idx];
    #pragma unroll
    for (int s = 0; s < NS; s++) {
        const float4 p = ((const float4*)part)[(size_t)s * 262144 + idx];
        r.x += p.x; r.y += p.y; r.z += p.z; r.w += p.w;
    }
    r.x += b4.x; r.y += b4.y; r.z += b4.z; r.w += b4.w;
    ((float4*)out)[idx] = r;
}

// ---------------------------------------------------------------- reduce+LN
// x1[row] = x[row] + bo + sum_s part[s][row];  h2[row] = LN(x1[row])*g+be
template <int NS>
__global__ __launch_bounds__(256) void reduce_ln_kernel(
    const float* __restrict__ part, const float* __restrict__ x,
    const float* __restrict__ bo, const float* __restrict__ g,
    const float* __restrict__ be, float* __restrict__ x1,
    __bf16* __restrict__ h2) {
    const int row = blockIdx.x;
    const int tid = threadIdx.x;
    const size_t rbase = (size_t)row * DDIM;
    float v[8];
    #pragma unroll
    for (int p = 0; p < 2; p++) {
        const int c = tid * 8 + p * 4;
        float4 r = *(const float4*)(x + rbase + c);
        const float4 b4 = *(const float4*)(bo + c);
        r.x += b4.x; r.y += b4.y; r.z += b4.z; r.w += b4.w;
        #pragma unroll
        for (int s = 0; s < NS; s++) {
            const float4 q = *(const float4*)(part + (size_t)s * BROWS * DDIM + rbase + c);
            r.x += q.x; r.y += q.y; r.z += q.z; r.w += q.w;
        }
        *(float4*)(x1 + rbase + c) = r;
        v[p * 4 + 0] = r.x; v[p * 4 + 1] = r.y; v[p * 4 + 2] = r.z; v[p * 4 + 3] = r.w;
    }
    float s = 0.f, s2 = 0.f;
    #pragma unroll
    for (int i = 0; i < 8; i++) { s += v[i]; s2 += v[i] * v[i]; }
    #pragma unroll
    for (int off = 32; off > 0; off >>= 1) {
        s  += __shfl_down(s, off);
        s2 += __shfl_down(s2, off);
    }
    __shared__ float ps[4], ps2[4];
    __shared__ float mean_s, rstd_s;
    const int lane = tid & 63, wv = tid >> 6;
    if (lane == 0) { ps[wv] = s; ps2[wv] = s2; }
    __syncthreads();
    if (tid == 0) {
        float S  = ps[0] + ps[1] + ps[2] + ps[3];
        float S2 = ps2[0] + ps2[1] + ps2[2] + ps2[3];
        float m  = S * (1.0f / DDIM);
        float var = S2 * (1.0f / DDIM) - m * m;
        mean_s = m;
        rstd_s = rsqrtf(var + LN_EPS);
    }
    __syncthreads();
    const float m = mean_s, r = rstd_s;
    const float4* g4 = (const float4*)g;
    const float4* b4 = (const float4*)be;
    float4 ga = g4[2 * tid], gb = g4[2 * tid + 1];
    float4 ba = b4[2 * tid], bb = b4[2 * tid + 1];
    bf16x8_t o;
    o[0] = (__bf16)((v[0] - m) * r * ga.x + ba.x);
    o[1] = (__bf16)((v[1] - m) * r * ga.y + ba.y);
    o[2] = (__bf16)((v[2] - m) * r * ga.z + ba.z);
    o[3] = (__bf16)((v[3] - m) * r * ga.w + ba.w);
    o[4] = (__bf16)((v[4] - m) * r * gb.x + bb.x);
    o[5] = (__bf16)((v[5] - m) * r * gb.y + bb.y);
    o[6] = (__bf16)((v[6] - m) * r * gb.z + bb.z);
    o[7] = (__bf16)((v[7] - m) * r * gb.w + bb.w);
    *(bf16x8_t*)(h2 + rbase + tid * 8) = o;
}

// ---------------------------------------------------------------- Attention
// qkv bf16 [512, 6144] (q|k|v per row, each [H,DH]); o bf16 [512, 2048].
__global__ __launch_bounds__(128) void attn_kernel(
    const __bf16* __restrict__ qkv, __bf16* __restrict__ o) {
    const int bh = blockIdx.x;  // b*H + h
    const int b = bh >> 4, h = bh & 15;
    const size_t base = (size_t)b * (3 * DDIM) + h * DHEAD;
    const int tid = threadIdx.x;
    __shared__ float ks[DHEAD], vs[DHEAD];
    ks[tid] = (float)qkv[base + DDIM + tid];
    vs[tid] = (float)qkv[base + 2 * DDIM + tid];
    __syncthreads();
    const float a = (float)qkv[base + tid] * 0.08838834764831845f;  // /sqrt(128)
    float den = 0.0f, num = 0.0f;
    #pragma unroll 8
    for (int j = 0; j < DHEAD; j++) {
        float e = __expf(a * ks[j]);
        den += e;
        num += e * vs[j];
    }
    o[(size_t)b * DDIM + h * DHEAD + tid] = (__bf16)(num / den);
}

// ---------------------------------------------------------------- launch
extern "C" void kernel_launch(void* const* d_in, const int* in_sizes, int n_in,
                              void* d_out, int out_size, void* d_ws, size_t ws_size,
                              hipStream_t stream) {
    const float* x   = (const float*)d_in[0];
    const float* Wq  = (const float*)d_in[1];
    const float* bq  = (const float*)d_in[2];
    const float* Wk  = (const float*)d_in[3];
    const float* bk  = (const float*)d_in[4];
    const float* Wv  = (const float*)d_in[5];
    const float* bv  = (const float*)d_in[6];
    const float* Wo  = (const float*)d_in[7];
    const float* bo  = (const float*)d_in[8];
    const float* W1  = (const float*)d_in[9];
    const float* b1  = (const float*)d_in[10];
    const float* W2  = (const float*)d_in[11];
    const float* b2  = (const float*)d_in[12];
    const float* g1  = (const float*)d_in[13];
    const float* be1 = (const float*)d_in[14];
    const float* g2  = (const float*)d_in[15];
    const float* be2 = (const float*)d_in[16];
    float* out = (float*)d_out;

    // ---- workspace layout (bytes), lifetime-overlapped ----
    char* base = (char*)d_ws;
    __bf16* bt_qkv = (__bf16*)(base + 32768);         // 25,165,824 B  [6144,2048]
    char*   slotA  = base + 32768 + 25165824;         // 33,554,432 B
    char*   slotB  = slotA + 33554432;                // 33,554,432 B
    // activations in dead regions:
    __bf16* h   = (__bf16*)(slotB + 0);               // bf16 [512,2048]
    __bf16* qkv = (__bf16*)(slotB + 2097152);         // bf16 [512,6144]
    __bf16* ob  = (__bf16*)(slotB + 8388608);         // bf16 [512,2048]
    float*  woP = (float*)(slotB + 10485760);         // fp32 [4][512,2048]
    float*  w2P = (float*)(slotB + 0);                // fp32 [4][512,2048] (W1t dead)
    float*  x1  = (float*)((char*)bt_qkv + 0);        // fp32 [512,2048]
    __bf16* h2  = (__bf16*)((char*)bt_qkv + 4194304); // bf16 [512,2048]
    __bf16* t   = (__bf16*)((char*)bt_qkv + 6291456); // bf16 [512,8192]
    __bf16* Wot = (__bf16*)slotA;                     // [2048,2048]
    __bf16* W1t = (__bf16*)slotB;                     // [8192,2048]
    __bf16* W2t = (__bf16*)slotA;                     // [2048,8192]

    // transposed bf16 weights: B^T[N,K]
    transpose_qkv_kernel<<<dim3(2, 32, 48), 256, 0, stream>>>(Wq, Wk, Wv, bt_qkv);
    transpose_kernel<<<dim3(32, 32, 1), 256, 0, stream>>>(Wo, Wot, DDIM, DDIM);

    // h = LN(x)
    ln_kernel<<<BROWS, 256, 0, stream>>>(x, g1, be1, h);

    // qkv = h @ [Wq|Wk|Wv] + [bq|bk|bv]   -> bf16 [512,6144]
    gemm_bt<3, 1, 1, 0, 0, 1><<<dim3(48, 4), 512, 0, stream>>>(
        h, DDIM, bt_qkv, bq, bk, bv, nullptr, qkv, 3 * DDIM);

    attn_kernel<<<BROWS * HHEADS, 128, 0, stream>>>(qkv, ob);

    // x1 = x + ob @ Wo + bo   (split-K=4 partials + fused reduce+LN)
    gemm_bt<3, 4, 0, 0, 0, 0><<<dim3(16, 4, 4), 512, 0, stream>>>(
        ob, DDIM, Wot, nullptr, nullptr, nullptr, nullptr, woP, DDIM);
    reduce_ln_kernel<4><<<BROWS, 256, 0, stream>>>(woP, x, bo, g2, be2, x1, h2);

    // late transposes into now-dead regions
    transpose_kernel<<<dim3(128, 32, 1), 256, 0, stream>>>(W1, W1t, DDIM, 4 * DDIM);
    transpose_kernel<<<dim3(32, 128, 1), 256, 0, stream>>>(W2, W2t, 4 * DDIM, DDIM);

    // t = relu(h2 @ W1 + b1)  -> bf16 [512,8192]
    gemm_bt<3, 1, 1, 1, 0, 0><<<dim3(64, 4), 512, 0, stream>>>(
        h2, DDIM, W1t, b1, nullptr, nullptr, nullptr, t, 4 * DDIM);

    // out = x1 + t @ W2 + b2   (split-K=4 partials + fused reduce)
    gemm_bt<3, 4, 0, 0, 0, 0><<<dim3(16, 4, 4), 512, 0, stream>>>(
        t, 4 * DDIM, W2t, nullptr, nullptr, nullptr, nullptr, w2P, DDIM);
    reduce_splitk<4><<<1024, 256, 0, stream>>>(w2P, x1, b2, out);
}

// Round 3
// 351.587 us; speedup vs baseline: 1.1406x; 1.0005x over previous
//
#include <hip/hip_runtime.h>
#include <hip/hip_bf16.h>
#include <math.h>

// Block_46643344834722: pre-norm attention block, B=512 D=2048 H=16 DH=128.
// R6: gemm K-loop restructured to ONE barrier per K-step: circular DEPTH=4,
// refill the slot consumed last step right after the barrier (loads overlap
// the whole read+MFMA phase), counted vmcnt(8) with end-taper (8/4/0).
// + s_setprio around MFMA cluster, + XCD-aware block swizzle on gemm grids.

#define DDIM 2048
#define HHEADS 16
#define DHEAD 128
#define BROWS 512
#define LN_EPS 1e-5f

typedef __bf16 bf16x8_t __attribute__((ext_vector_type(8)));
typedef float f32x4_t __attribute__((ext_vector_type(4)));

#define GLD16(gptr, lptr)                                                     \
    __builtin_amdgcn_global_load_lds(                                         \
        (const __attribute__((address_space(1))) void*)(gptr),                \
        (__attribute__((address_space(3))) void*)(lptr), 16, 0, 0)

// ---------------------------------------------------------------- LayerNorm
__global__ __launch_bounds__(256) void ln_kernel(const float* __restrict__ x,
                                                 const float* __restrict__ g,
                                                 const float* __restrict__ b,
                                                 __bf16* __restrict__ out) {
    const int row = blockIdx.x;
    const int tid = threadIdx.x;
    const float4* x4 = (const float4*)(x + (size_t)row * DDIM);
    float4 a = x4[2 * tid];
    float4 c = x4[2 * tid + 1];
    float s  = a.x + a.y + a.z + a.w + c.x + c.y + c.z + c.w;
    float s2 = a.x*a.x + a.y*a.y + a.z*a.z + a.w*a.w
             + c.x*c.x + c.y*c.y + c.z*c.z + c.w*c.w;
    #pragma unroll
    for (int off = 32; off > 0; off >>= 1) {
        s  += __shfl_down(s, off);
        s2 += __shfl_down(s2, off);
    }
    __shared__ float ps[4], ps2[4];
    __shared__ float mean_s, rstd_s;
    const int lane = tid & 63, w = tid >> 6;
    if (lane == 0) { ps[w] = s; ps2[w] = s2; }
    __syncthreads();
    if (tid == 0) {
        float S  = ps[0] + ps[1] + ps[2] + ps[3];
        float S2 = ps2[0] + ps2[1] + ps2[2] + ps2[3];
        float m  = S * (1.0f / DDIM);
        float var = S2 * (1.0f / DDIM) - m * m;
        mean_s = m;
        rstd_s = rsqrtf(var + LN_EPS);
    }
    __syncthreads();
    const float m = mean_s, r = rstd_s;
    const float4* g4 = (const float4*)g;
    const float4* b4 = (const float4*)b;
    float4 ga = g4[2 * tid], gb = g4[2 * tid + 1];
    float4 ba = b4[2 * tid], bb = b4[2 * tid + 1];
    bf16x8_t o;
    o[0] = (__bf16)((a.x - m) * r * ga.x + ba.x);
    o[1] = (__bf16)((a.y - m) * r * ga.y + ba.y);
    o[2] = (__bf16)((a.z - m) * r * ga.z + ba.z);
    o[3] = (__bf16)((a.w - m) * r * ga.w + ba.w);
    o[4] = (__bf16)((c.x - m) * r * gb.x + bb.x);
    o[5] = (__bf16)((c.y - m) * r * gb.y + bb.y);
    o[6] = (__bf16)((c.z - m) * r * gb.z + bb.z);
    o[7] = (__bf16)((c.w - m) * r * gb.w + bb.w);
    *(bf16x8_t*)(out + (size_t)row * DDIM + tid * 8) = o;
}

// ---------------------------------------------------------------- Transpose
// src fp32 [R,C] (batched) -> dst bf16 [C,R] (batched, stride R*C).
__global__ __launch_bounds__(256) void transpose_kernel(
    const float* __restrict__ src, __bf16* __restrict__ dst, int R, int C) {
    __shared__ float tile[64][65];
    const size_t bofs = (size_t)blockIdx.z * R * C;
    src += bofs;
    dst += bofs;
    const int c0 = blockIdx.x * 64, r0 = blockIdx.y * 64;
    const int t = threadIdx.x;
    const int rr = t >> 4, cc = (t & 15) * 4;
    #pragma unroll
    for (int p = 0; p < 4; p++) {
        const float4 v =
            *(const float4*)(src + (size_t)(r0 + rr + 16 * p) * C + c0 + cc);
        tile[rr + 16 * p][cc]     = v.x;
        tile[rr + 16 * p][cc + 1] = v.y;
        tile[rr + 16 * p][cc + 2] = v.z;
        tile[rr + 16 * p][cc + 3] = v.w;
    }
    __syncthreads();
    const int slot = t & 7;
    #pragma unroll
    for (int p = 0; p < 2; p++) {
        const int c = (t >> 3) + 32 * p;
        bf16x8_t o;
        #pragma unroll
        for (int j = 0; j < 8; j++)
            o[j] = (__bf16)tile[slot * 8 + j][c];
        *(bf16x8_t*)(dst + (size_t)(c0 + c) * R + r0 + slot * 8) = o;
    }
}

// Merged q/k/v weight transpose: z = which*16 + head; [2048,128] -> transposed
__global__ __launch_bounds__(256) void transpose_qkv_kernel(
    const float* __restrict__ Wq, const float* __restrict__ Wk,
    const float* __restrict__ Wv, __bf16* __restrict__ dstall) {
    __shared__ float tile[64][65];
    const int z = blockIdx.z, which = z >> 4, hd = z & 15;
    const float* src = (which == 0) ? Wq : (which == 1) ? Wk : Wv;
    src += (size_t)hd * DDIM * DHEAD;
    __bf16* dst = dstall + (size_t)which * DDIM * DDIM + (size_t)hd * DDIM * DHEAD;
    const int R = DDIM, C = DHEAD;
    const int c0 = blockIdx.x * 64, r0 = blockIdx.y * 64;
    const int t = threadIdx.x;
    const int rr = t >> 4, cc = (t & 15) * 4;
    #pragma unroll
    for (int p = 0; p < 4; p++) {
        const float4 v =
            *(const float4*)(src + (size_t)(r0 + rr + 16 * p) * C + c0 + cc);
        tile[rr + 16 * p][cc]     = v.x;
        tile[rr + 16 * p][cc + 1] = v.y;
        tile[rr + 16 * p][cc + 2] = v.z;
        tile[rr + 16 * p][cc + 3] = v.w;
    }
    __syncthreads();
    const int slot = t & 7;
    #pragma unroll
    for (int p = 0; p < 2; p++) {
        const int c = (t >> 3) + 32 * p;
        bf16x8_t o;
        #pragma unroll
        for (int j = 0; j < 8; j++)
            o[j] = (__bf16)tile[slot * 8 + j][c];
        *(bf16x8_t*)(dst + (size_t)(c0 + c) * R + r0 + slot * 8) = o;
    }
}

// ---------------------------------------------------------------- GEMM (B^T)
// C[M,N] = A[M,K] @ Bt[N,K]^T (+bias +Res, relu?).  bf16 in, fp32 acc.
// 128x128 tile, 512 threads (8 waves: 4 wave-tiles x 2 k-halves).
// BK=64 stages, both-sides XOR swizzle (pre-swizzled global source,
// swizzled ds_read_b128 -> 2-way banks = free).
// ONE barrier per K-step: circular DEPTH=4; after the barrier refill the
// slot consumed LAST step (data for step ks+DEPTH-1) so loads overlap the
// read+MFMA phase.  Counted vmcnt: 8 steady, taper 4/0 at the last 2 steps.
// SPLITZ>1: blockIdx.z takes K/SPLITZ slice, writes raw fp32 partials.
template <int SPLITZ, int OUT_BF16, int RELU, int RES, int BIAS3>
__global__ __launch_bounds__(512) void gemm_bt(
    const __bf16* __restrict__ A, int K,
    const __bf16* __restrict__ Bt,
    const float* __restrict__ bias, const float* __restrict__ biasB,
    const float* __restrict__ biasC,
    const float* __restrict__ Res,
    void* __restrict__ Cout, int N) {
    constexpr int TM = 128, TN = 128, DEPTH = 4;
    constexpr int STG = (TM + TN) * 64;  // bf16 elems per stage (BK=64)
    __shared__ __align__(16) __bf16 smem[DEPTH * STG];  // 128 KiB

    const int tid = threadIdx.x;
    const int w = tid >> 6, lane = tid & 63;

    // ---- XCD-aware block swizzle: same-x (same weight cols) per XCD ----
    const int gx = gridDim.x, gy = gridDim.y, gz = gridDim.z;
    {
    }
    int l = blockIdx.x + gx * (blockIdx.y + gy * blockIdx.z);
    const int xcd = l & 7;
    int i0 = l >> 3;
    const int by = i0 % gy; i0 /= gy;
    const int bz = i0 % gz; i0 /= gz;
    const int bx = xcd * (gx >> 3) + i0;

    const int m0 = by * TM, n0 = bx * TN;

    const int Kloc = K / SPLITZ;
    const int kb = bz * Kloc;
    const int NK = Kloc / 64;

    constexpr int NT = (TM + TN) / 8;  // 8-row (1KB) chunks per stage
    constexpr int NI = NT / 8;         // chunks per wave (4)

    // staging: chunk t covers rows 8t..8t+7 (A rows then B rows).
    // lane l -> row 8t+(l>>3); source k-slot pre-swizzled (l&7)^(l>>3).
    const int srow = lane >> 3;
    const int sslot = (lane & 7) ^ srow;

    const __bf16* srcs[NI];
    int toff[NI];
    #pragma unroll
    for (int i = 0; i < NI; i++) {
        const int t = w + 8 * i;
        toff[i] = t * 512;  // 8 rows * 64 elems
        const int r = t * 8 + srow;
        srcs[i] = (r < TM)
                      ? A + (size_t)(m0 + r) * K + kb + sslot * 8
                      : Bt + (size_t)(n0 + r - TM) * K + kb + sslot * 8;
    }

    constexpr int MI = 4, NJ = 4;        // 64x64 wave-tile in 16-units
    const int wg = w & 3, kh = w >> 2;   // wave-tile id, k-half id
    const int wm = (wg >> 1) * 64, wn = (wg & 1) * 64;
    const int fm = lane & 15, quad = lane >> 4;
    const int f7 = fm & 7;

    // fragment LDS byte offsets within a stage (own k-half only):
    // byte = row*128 + ((kh*4+quad) ^ (row&7))*16
    const int sl = ((kh * 4 + quad) ^ f7) * 16;
    int aoff[MI], boff[NJ];
    #pragma unroll
    for (int i = 0; i < MI; i++)
        aoff[i] = (wm + 16 * i + fm) * 128 + sl;
    #pragma unroll
    for (int j = 0; j < NJ; j++)
        boff[j] = (TM + wn + 16 * j + fm) * 128 + sl;

    f32x4_t acc[MI][NJ] = {};

    // prologue: fill all DEPTH stages
    #pragma unroll
    for (int d = 0; d < DEPTH; d++)
        #pragma unroll
        for (int i = 0; i < NI; i++)
            GLD16(srcs[i] + d * 64, smem + d * STG + toff[i]);

    for (int ks = 0; ks < NK; ks++) {
        const char* st = (const char*)smem + (ks % DEPTH) * (STG * 2);
        // single sync point: slot ks ready (own vmcnt + barrier joins all
        // waves), AND all waves finished reading slot ks-1 (their reads
        // were consumed by MFMAs before they reached this barrier).
        if (ks < NK - 2)
            asm volatile("s_waitcnt vmcnt(%0)\n\ts_barrier"
                         :: "i"((DEPTH - 2) * NI) : "memory");
        else if (ks == NK - 2)
            asm volatile("s_waitcnt vmcnt(%0)\n\ts_barrier"
                         :: "i"(NI) : "memory");
        else
            asm volatile("s_waitcnt vmcnt(0)\n\ts_barrier" ::: "memory");

        // refill the slot consumed last step with data for step ks+DEPTH-1;
        // these loads fly underneath this step's ds_read + MFMA.
        if (ks >= 1 && ks + DEPTH - 1 < NK) {
            __bf16* dst = smem + ((ks - 1) % DEPTH) * STG;
            #pragma unroll
            for (int i = 0; i < NI; i++)
                GLD16(srcs[i] + (size_t)(ks + DEPTH - 1) * 64, dst + toff[i]);
        }

        bf16x8_t a[MI], b[NJ];
        #pragma unroll
        for (int i = 0; i < MI; i++)
            a[i] = *(const bf16x8_t*)(st + aoff[i]);
        #pragma unroll
        for (int j = 0; j < NJ; j++)
            b[j] = *(const bf16x8_t*)(st + boff[j]);
        __builtin_amdgcn_s_setprio(1);
        #pragma unroll
        for (int i = 0; i < MI; i++)
            #pragma unroll
            for (int j = 0; j < NJ; j++)
                acc[i][j] = __builtin_amdgcn_mfma_f32_16x16x32_bf16(
                    a[i], b[j], acc[i][j], 0, 0, 0);
        __builtin_amdgcn_s_setprio(0);
    }

    // ---- merge the two k-half accumulators through LDS (reuses stages) ----
    char* mrg = (char*)smem + wg * 16384;
    __syncthreads();  // all reads of the final slot complete before reuse
    if (kh == 1) {
        #pragma unroll
        for (int i = 0; i < MI; i++)
            #pragma unroll
            for (int j = 0; j < NJ; j++)
                *(f32x4_t*)(mrg + (((i * NJ + j) * 64) + lane) * 16) = acc[i][j];
    }
    __syncthreads();
    if (kh == 1) return;
    #pragma unroll
    for (int i = 0; i < MI; i++)
        #pragma unroll
        for (int j = 0; j < NJ; j++) {
            const f32x4_t p = *(const f32x4_t*)(mrg + (((i * NJ + j) * 64) + lane) * 16);
            acc[i][j][0] += p[0]; acc[i][j][1] += p[1];
            acc[i][j][2] += p[2]; acc[i][j][3] += p[3];
        }

    // epilogue: C/D layout col=fm, row=quad*4+r  (waves 0..3 only)
    if (SPLITZ > 1) {
        float* P = (float*)Cout + (size_t)bz * (gy * TM) * N;
        #pragma unroll
        for (int i = 0; i < MI; i++)
            #pragma unroll
            for (int j = 0; j < NJ; j++) {
                const int col = n0 + wn + 16 * j + fm;
                #pragma unroll
                for (int r = 0; r < 4; r++) {
                    const int row = m0 + wm + 16 * i + quad * 4 + r;
                    P[(size_t)row * N + col] = acc[i][j][r];
                }
            }
    } else {
        const float* bp = bias;
        if (BIAS3) {  // q|k|v segment select, uniform per block (n0 mult of 128)
            const int seg = n0 >> 11;
            bp = (seg == 0) ? bias : (seg == 1) ? biasB : biasC;
        }
        #pragma unroll
        for (int i = 0; i < MI; i++)
            #pragma unroll
            for (int j = 0; j < NJ; j++) {
                const int col = n0 + wn + 16 * j + fm;
                const float bcol = BIAS3 ? bp[col & 2047] : bp[col];
                #pragma unroll
                for (int r = 0; r < 4; r++) {
                    const int row = m0 + wm + 16 * i + quad * 4 + r;
                    float val = acc[i][j][r] + bcol;
                    if (RES) val += Res[(size_t)row * N + col];
                    if (RELU) val = fmaxf(val, 0.0f);
                    if (OUT_BF16)
                        ((__bf16*)Cout)[(size_t)row * N + col] = (__bf16)val;
                    else
                        ((float*)Cout)[(size_t)row * N + col] = val;
                }
            }
    }
}

// ---------------------------------------------------------------- split-K sum
// out[512,2048] = Res + bias(per-col) + sum_s part[s]   (float4 per thread)
template <int NS>
__global__ __launch_bounds__(256) void reduce_splitk(
    const float* __restrict__ part, const float* __restrict__ Res,
    const float* __restrict__ bias, float* __restrict__ out) {
    const int idx = blockIdx.x * 256 + threadIdx.x;  // 0..262143 float4s
    const float4 b4 = ((const float4*)bias)[idx & 511];
    float4 r = ((const float4*)Res)[idx];
    #pragma unroll
    for (int s = 0; s < NS; s++) {
        const float4 p = ((const float4*)part)[(size_t)s * 262144 + idx];
        r.x += p.x; r.y += p.y; r.z += p.z; r.w += p.w;
    }
    r.x += b4.x; r.y += b4.y; r.z += b4.z; r.w += b4.w;
    ((float4*)out)[idx] = r;
}

// ---------------------------------------------------------------- reduce+LN
// x1[row] = x[row] + bo + sum_s part[s][row];  h2[row] = LN(x1[row])*g+be
template <int NS>
__global__ __launch_bounds__(256) void reduce_ln_kernel(
    const float* __restrict__ part, const float* __restrict__ x,
    const float* __restrict__ bo, const float* __restrict__ g,
    const float* __restrict__ be, float* __restrict__ x1,
    __bf16* __restrict__ h2) {
    const int row = blockIdx.x;
    const int tid = threadIdx.x;
    const size_t rbase = (size_t)row * DDIM;
    float v[8];
    #pragma unroll
    for (int p = 0; p < 2; p++) {
        const int c = tid * 8 + p * 4;
        float4 r = *(const float4*)(x + rbase + c);
        const float4 b4 = *(const float4*)(bo + c);
        r.x += b4.x; r.y += b4.y; r.z += b4.z; r.w += b4.w;
        #pragma unroll
        for (int s = 0; s < NS; s++) {
            const float4 q = *(const float4*)(part + (size_t)s * BROWS * DDIM + rbase + c);
            r.x += q.x; r.y += q.y; r.z += q.z; r.w += q.w;
        }
        *(float4*)(x1 + rbase + c) = r;
        v[p * 4 + 0] = r.x; v[p * 4 + 1] = r.y; v[p * 4 + 2] = r.z; v[p * 4 + 3] = r.w;
    }
    float s = 0.f, s2 = 0.f;
    #pragma unroll
    for (int i = 0; i < 8; i++) { s += v[i]; s2 += v[i] * v[i]; }
    #pragma unroll
    for (int off = 32; off > 0; off >>= 1) {
        s  += __shfl_down(s, off);
        s2 += __shfl_down(s2, off);
    }
    __shared__ float ps[4], ps2[4];
    __shared__ float mean_s, rstd_s;
    const int lane = tid & 63, wv = tid >> 6;
    if (lane == 0) { ps[wv] = s; ps2[wv] = s2; }
    __syncthreads();
    if (tid == 0) {
        float S  = ps[0] + ps[1] + ps[2] + ps[3];
        float S2 = ps2[0] + ps2[1] + ps2[2] + ps2[3];
        float m  = S * (1.0f / DDIM);
        float var = S2 * (1.0f / DDIM) - m * m;
        mean_s = m;
        rstd_s = rsqrtf(var + LN_EPS);
    }
    __syncthreads();
    const float m = mean_s, r = rstd_s;
    const float4* g4 = (const float4*)g;
    const float4* b4 = (const float4*)be;
    float4 ga = g4[2 * tid], gb = g4[2 * tid + 1];
    float4 ba = b4[2 * tid], bb = b4[2 * tid + 1];
    bf16x8_t o;
    o[0] = (__bf16)((v[0] - m) * r * ga.x + ba.x);
    o[1] = (__bf16)((v[1] - m) * r * ga.y + ba.y);
    o[2] = (__bf16)((v[2] - m) * r * ga.z + ba.z);
    o[3] = (__bf16)((v[3] - m) * r * ga.w + ba.w);
    o[4] = (__bf16)((v[4] - m) * r * gb.x + bb.x);
    o[5] = (__bf16)((v[5] - m) * r * gb.y + bb.y);
    o[6] = (__bf16)((v[6] - m) * r * gb.z + bb.z);
    o[7] = (__bf16)((v[7] - m) * r * gb.w + bb.w);
    *(bf16x8_t*)(h2 + rbase + tid * 8) = o;
}

// ---------------------------------------------------------------- Attention
// qkv bf16 [512, 6144] (q|k|v per row, each [H,DH]); o bf16 [512, 2048].
__global__ __launch_bounds__(128) void attn_kernel(
    const __bf16* __restrict__ qkv, __bf16* __restrict__ o) {
    const int bh = blockIdx.x;  // b*H + h
    const int b = bh >> 4, h = bh & 15;
    const size_t base = (size_t)b * (3 * DDIM) + h * DHEAD;
    const int tid = threadIdx.x;
    __shared__ float ks[DHEAD], vs[DHEAD];
    ks[tid] = (float)qkv[base + DDIM + tid];
    vs[tid] = (float)qkv[base + 2 * DDIM + tid];
    __syncthreads();
    const float a = (float)qkv[base + tid] * 0.08838834764831845f;  // /sqrt(128)
    float den = 0.0f, num = 0.0f;
    #pragma unroll 8
    for (int j = 0; j < DHEAD; j++) {
        float e = __expf(a * ks[j]);
        den += e;
        num += e * vs[j];
    }
    o[(size_t)b * DDIM + h * DHEAD + tid] = (__bf16)(num / den);
}

// ---------------------------------------------------------------- launch
extern "C" void kernel_launch(void* const* d_in, const int* in_sizes, int n_in,
                              void* d_out, int out_size, void* d_ws, size_t ws_size,
                              hipStream_t stream) {
    const float* x   = (const float*)d_in[0];
    const float* Wq  = (const float*)d_in[1];
    const float* bq  = (const float*)d_in[2];
    const float* Wk  = (const float*)d_in[3];
    const float* bk  = (const float*)d_in[4];
    const float* Wv  = (const float*)d_in[5];
    const float* bv  = (const float*)d_in[6];
    const float* Wo  = (const float*)d_in[7];
    const float* bo  = (const float*)d_in[8];
    const float* W1  = (const float*)d_in[9];
    const float* b1  = (const float*)d_in[10];
    const float* W2  = (const float*)d_in[11];
    const float* b2  = (const float*)d_in[12];
    const float* g1  = (const float*)d_in[13];
    const float* be1 = (const float*)d_in[14];
    const float* g2  = (const float*)d_in[15];
    const float* be2 = (const float*)d_in[16];
    float* out = (float*)d_out;

    // ---- workspace layout (bytes), lifetime-overlapped ----
    char* base = (char*)d_ws;
    __bf16* bt_qkv = (__bf16*)(base + 32768);         // 25,165,824 B  [6144,2048]
    char*   slotA  = base + 32768 + 25165824;         // 33,554,432 B
    char*   slotB  = slotA + 33554432;                // 33,554,432 B
    // activations in dead regions:
    __bf16* h   = (__bf16*)(slotB + 0);               // bf16 [512,2048]
    __bf16* qkv = (__bf16*)(slotB + 2097152);         // bf16 [512,6144]
    __bf16* ob  = (__bf16*)(slotB + 8388608);         // bf16 [512,2048]
    float*  woP = (float*)(slotB + 10485760);         // fp32 [4][512,2048]
    float*  w2P = (float*)(slotB + 0);                // fp32 [4][512,2048] (W1t dead)
    float*  x1  = (float*)((char*)bt_qkv + 0);        // fp32 [512,2048]
    __bf16* h2  = (__bf16*)((char*)bt_qkv + 4194304); // bf16 [512,2048]
    __bf16* t   = (__bf16*)((char*)bt_qkv + 6291456); // bf16 [512,8192]
    __bf16* Wot = (__bf16*)slotA;                     // [2048,2048]
    __bf16* W1t = (__bf16*)slotB;                     // [8192,2048]
    __bf16* W2t = (__bf16*)slotA;                     // [2048,8192]

    // transposed bf16 weights: B^T[N,K]
    transpose_qkv_kernel<<<dim3(2, 32, 48), 256, 0, stream>>>(Wq, Wk, Wv, bt_qkv);
    transpose_kernel<<<dim3(32, 32, 1), 256, 0, stream>>>(Wo, Wot, DDIM, DDIM);

    // h = LN(x)
    ln_kernel<<<BROWS, 256, 0, stream>>>(x, g1, be1, h);

    // qkv = h @ [Wq|Wk|Wv] + [bq|bk|bv]   -> bf16 [512,6144]
    gemm_bt<1, 1, 0, 0, 1><<<dim3(48, 4), 512, 0, stream>>>(
        h, DDIM, bt_qkv, bq, bk, bv, nullptr, qkv, 3 * DDIM);

    attn_kernel<<<BROWS * HHEADS, 128, 0, stream>>>(qkv, ob);

    // x1 = x + ob @ Wo + bo   (split-K=4 partials + fused reduce+LN)
    gemm_bt<4, 0, 0, 0, 0><<<dim3(16, 4, 4), 512, 0, stream>>>(
        ob, DDIM, Wot, nullptr, nullptr, nullptr, nullptr, woP, DDIM);
    reduce_ln_kernel<4><<<BROWS, 256, 0, stream>>>(woP, x, bo, g2, be2, x1, h2);

    // late transposes into now-dead regions
    transpose_kernel<<<dim3(128, 32, 1), 256, 0, stream>>>(W1, W1t, DDIM, 4 * DDIM);
    transpose_kernel<<<dim3(32, 128, 1), 256, 0, stream>>>(W2, W2t, 4 * DDIM, DDIM);

    // t = relu(h2 @ W1 + b1)  -> bf16 [512,8192]
    gemm_bt<1, 1, 1, 0, 0><<<dim3(64, 4), 512, 0, stream>>>(
        h2, DDIM, W1t, b1, nullptr, nullptr, nullptr, t, 4 * DDIM);

    // out = x1 + t @ W2 + b2   (split-K=4 partials + fused reduce)
    gemm_bt<4, 0, 0, 0, 0><<<dim3(16, 4, 4), 512, 0, stream>>>(
        t, 4 * DDIM, W2t, nullptr, nullptr, nullptr, nullptr, w2P, DDIM);
    reduce_splitk<4><<<1024, 256, 0, stream>>>(w2P, x1, b2, out);
}